// Round 3
// baseline (585.468 us; speedup 1.0000x reference)
//
#include <hip/hip_runtime.h>

// SpeakerLoss: d[i] = ||vs_i - other_vs_i||^2 ; same-speaker keep d,
// different-speaker hinge max(L - d, 0); output = mean over B. L = 1.0.
//
// v3 = MEASUREMENT PROBE. Kernel body identical to v2b (8 lanes/row,
// 32 B/lane/chunk, x2 unroll, 2048 blocks, NT loads). The partial pass is
// launched TWICE (second into partials[2048..4095]); finalize sums 4096
// partials scaled by 0.5/B, so the result is unchanged (to ~1 ulp).
// Purpose: dur_us(v3) - dur_us(v2b) = true cost K of one streaming pass,
// which the rocprof top-k filter has been hiding behind the harness fills.

#define BLOCKS   2048
#define THREADS  256
#define MARGIN_L 1.0f

typedef float floatx4 __attribute__((ext_vector_type(4)));

__global__ __launch_bounds__(THREADS) void speaker_loss_partial(
    const int* __restrict__ s,
    const floatx4* __restrict__ vs4,
    const int* __restrict__ os,
    const floatx4* __restrict__ ovs4,
    float* __restrict__ partials,
    int B) {
    const int n8 = B * 8;  // 32-byte chunks per matrix (8e6 < 2^31)
    const int stride = gridDim.x * blockDim.x;
    int i = blockIdx.x * blockDim.x + threadIdx.x;
    const float mask = ((threadIdx.x & 7) == 0) ? 1.0f : 0.0f;

    float acc = 0.0f;

    auto chunk = [&](int idx) {
        const int row = idx >> 3;  // 8 lanes x 32 B = one 256 B row
        floatx4 a0 = __builtin_nontemporal_load(&vs4[2 * idx]);
        floatx4 a1 = __builtin_nontemporal_load(&vs4[2 * idx + 1]);
        floatx4 b0 = __builtin_nontemporal_load(&ovs4[2 * idx]);
        floatx4 b1 = __builtin_nontemporal_load(&ovs4[2 * idx + 1]);
        floatx4 d0 = a0 - b0;
        floatx4 d1 = a1 - b1;
        float p = d0.x * d0.x + d0.y * d0.y + d0.z * d0.z + d0.w * d0.w
                + d1.x * d1.x + d1.y * d1.y + d1.z * d1.z + d1.w * d1.w;
        // Butterfly sum within the 8-lane row group (masks 1..4 stay
        // inside each aligned 8-lane group of the wave64).
        p += __shfl_xor(p, 1);
        p += __shfl_xor(p, 2);
        p += __shfl_xor(p, 4);
        // All 8 lanes hold d(row); hinge, count once per row via mask.
        float v = (s[row] == os[row]) ? p : fmaxf(MARGIN_L - p, 0.0f);
        acc += v * mask;
    };

    // Main loop: two independent chunks per pass (independent load +
    // shuffle chains). After exit at most one chunk remains per thread.
    for (; i + stride < n8; i += 2 * stride) {
        chunk(i);
        chunk(i + stride);
    }
    if (i < n8) chunk(i);

    // acc is nonzero only on lanes 0,8,16,...,56 of each wave.
    acc += __shfl_xor(acc, 8);
    acc += __shfl_xor(acc, 16);
    acc += __shfl_xor(acc, 32);
    // lane 0 of each wave now holds the wave total.

    __shared__ float warp_sums[THREADS / 64];
    const int wave = threadIdx.x >> 6;
    if ((threadIdx.x & 63) == 0) warp_sums[wave] = acc;
    __syncthreads();

    if (threadIdx.x == 0) {
        float t = 0.0f;
#pragma unroll
        for (int w = 0; w < THREADS / 64; ++w) t += warp_sums[w];
        partials[blockIdx.x] = t;
    }
}

__global__ __launch_bounds__(THREADS) void speaker_loss_finalize(
    const float* __restrict__ partials, int n, float* __restrict__ out,
    float scale) {
    float acc = 0.0f;
    for (int i = threadIdx.x; i < n; i += blockDim.x) acc += partials[i];
#pragma unroll
    for (int m = 1; m < 64; m <<= 1) acc += __shfl_xor(acc, m);

    __shared__ float warp_sums[THREADS / 64];
    const int wave = threadIdx.x >> 6;
    if ((threadIdx.x & 63) == 0) warp_sums[wave] = acc;
    __syncthreads();

    if (threadIdx.x == 0) {
        float t = 0.0f;
#pragma unroll
        for (int w = 0; w < THREADS / 64; ++w) t += warp_sums[w];
        out[0] = t * scale;
    }
}

extern "C" void kernel_launch(void* const* d_in, const int* in_sizes, int n_in,
                              void* d_out, int out_size, void* d_ws, size_t ws_size,
                              hipStream_t stream) {
    const int*     s    = (const int*)d_in[0];
    const floatx4* vs4  = (const floatx4*)d_in[1];
    const int*     os   = (const int*)d_in[2];
    const floatx4* ovs4 = (const floatx4*)d_in[3];
    float* out = (float*)d_out;
    float* partials = (float*)d_ws;
    const int B = in_sizes[0];

    // Pass 1 and pass 2 are identical full streaming passes; the delta in
    // total dur_us vs the single-pass build measures one pass exactly.
    speaker_loss_partial<<<BLOCKS, THREADS, 0, stream>>>(s, vs4, os, ovs4,
                                                         partials, B);
    speaker_loss_partial<<<BLOCKS, THREADS, 0, stream>>>(s, vs4, os, ovs4,
                                                         partials + BLOCKS, B);
    speaker_loss_finalize<<<1, THREADS, 0, stream>>>(partials, 2 * BLOCKS, out,
                                                     0.5f / (float)B);
}

// Round 4
// 482.769 us; speedup vs baseline: 1.2127x; 1.2127x over previous
//
#include <hip/hip_runtime.h>
#include <hip/hip_bf16.h>

// SpeakerLoss: d[i] = ||vs_i - other_vs_i||^2 ; same-speaker keep d,
// different-speaker hinge max(L - d, 0); output = mean over B. L = 1.0.
//
// v4 = revert to the best-measured single-pass kernel (round-0, 482.9 us).
// Probe round established: one streaming pass costs ~94 us (~5.5 TB/s on
// 520 MB); the remaining ~390 us of the timed window is harness poison/
// restore traffic (1.024 GB fill = 152 us @ 84% peak in top-5) that no
// kernel edit can affect. Structural variants (8 vs 16 lanes/row, NT vs
// plain loads, 1024 vs 2048 blocks) all landed within the +/-8 us fill-
// jitter noise band -> this config is at the BW plateau.
//
// Layout: 16 lanes per row (D=64 floats = 16 float4), one float4 per lane
// -> wave reads 1 KiB contiguous per input array (fully coalesced).
// Grid-stride loop, register accumulation, block partials to d_ws, tiny
// second kernel for the final reduction (no atomics, deterministic).

#define BLOCKS   1024
#define THREADS  256
#define MARGIN_L 1.0f

__global__ __launch_bounds__(THREADS) void speaker_loss_partial(
    const int* __restrict__ s,
    const float4* __restrict__ vs4,
    const int* __restrict__ os,
    const float4* __restrict__ ovs4,
    float* __restrict__ partials,
    int B) {
    const int n4 = B * 16;  // total float4 elements per matrix (16e6 < 2^31)
    const int stride = gridDim.x * blockDim.x;
    int i = blockIdx.x * blockDim.x + threadIdx.x;
    const float mask = ((threadIdx.x & 15) == 0) ? 1.0f : 0.0f;

    float acc = 0.0f;
    for (; i < n4; i += stride) {
        const int row = i >> 4;
        float4 a = vs4[i];
        float4 b = ovs4[i];
        float dx = a.x - b.x;
        float dy = a.y - b.y;
        float dz = a.z - b.z;
        float dw = a.w - b.w;
        float p = dx * dx + dy * dy + dz * dz + dw * dw;
        // Butterfly sum within the 16-lane row group (wave64: masks 1..8
        // only exchange inside each aligned 16-lane group).
        p += __shfl_xor(p, 1);
        p += __shfl_xor(p, 2);
        p += __shfl_xor(p, 4);
        p += __shfl_xor(p, 8);
        // All 16 lanes now hold d(row); hinge, count once per row via mask.
        float v = (s[row] == os[row]) ? p : fmaxf(MARGIN_L - p, 0.0f);
        acc += v * mask;
    }

    // acc is nonzero only on lanes 0,16,32,48 of each wave.
    acc += __shfl_xor(acc, 16);
    acc += __shfl_xor(acc, 32);
    // lane 0 of each wave now holds the wave total.

    __shared__ float warp_sums[THREADS / 64];
    const int wave = threadIdx.x >> 6;
    if ((threadIdx.x & 63) == 0) warp_sums[wave] = acc;
    __syncthreads();

    if (threadIdx.x == 0) {
        float t = 0.0f;
#pragma unroll
        for (int w = 0; w < THREADS / 64; ++w) t += warp_sums[w];
        partials[blockIdx.x] = t;
    }
}

__global__ __launch_bounds__(THREADS) void speaker_loss_finalize(
    const float* __restrict__ partials, int n, float* __restrict__ out,
    float invB) {
    float acc = 0.0f;
    for (int i = threadIdx.x; i < n; i += blockDim.x) acc += partials[i];
#pragma unroll
    for (int m = 1; m < 64; m <<= 1) acc += __shfl_xor(acc, m);

    __shared__ float warp_sums[THREADS / 64];
    const int wave = threadIdx.x >> 6;
    if ((threadIdx.x & 63) == 0) warp_sums[wave] = acc;
    __syncthreads();

    if (threadIdx.x == 0) {
        float t = 0.0f;
#pragma unroll
        for (int w = 0; w < THREADS / 64; ++w) t += warp_sums[w];
        out[0] = t * invB;
    }
}

extern "C" void kernel_launch(void* const* d_in, const int* in_sizes, int n_in,
                              void* d_out, int out_size, void* d_ws, size_t ws_size,
                              hipStream_t stream) {
    const int*    s    = (const int*)d_in[0];
    const float4* vs4  = (const float4*)d_in[1];
    const int*    os   = (const int*)d_in[2];
    const float4* ovs4 = (const float4*)d_in[3];
    float* out = (float*)d_out;
    float* partials = (float*)d_ws;
    const int B = in_sizes[0];

    speaker_loss_partial<<<BLOCKS, THREADS, 0, stream>>>(s, vs4, os, ovs4,
                                                         partials, B);
    speaker_loss_finalize<<<1, THREADS, 0, stream>>>(partials, BLOCKS, out,
                                                     1.0f / (float)B);
}